// Round 9
// baseline (316.014 us; speedup 1.0000x reference)
//
#include <hip/hip_runtime.h>
#include <hip/hip_bf16.h>
#include <math.h>

#define HIDDEN 1280
#define HEADS 16
#define HD 80           // head dim
#define HALF 40
#define BB 2
#define NN 2048
#define MROWS (BB * NN) // 4096
// 1/sqrt(80) * log2(e): scores come out in log2 domain -> exp2 directly
#define QSCALE ((float)(0.11180339887498949 * 1.4426950408889634))

typedef __attribute__((ext_vector_type(8))) _Float16 f16x8;
typedef __attribute__((ext_vector_type(4))) float f32x4;

#define AS1 __attribute__((address_space(1)))
#define AS3 __attribute__((address_space(3)))

// Split fp32 into fp16 hi + fp16 lo (hi+lo carries ~22 mantissa bits).
__device__ __forceinline__ void splitf16(float x, ushort& hi, ushort& lo) {
    _Float16 h = (_Float16)x;
    _Float16 l = (_Float16)(x - (float)h);
    hi = __builtin_bit_cast(ushort, h);
    lo = __builtin_bit_cast(ushort, l);
}

__device__ __forceinline__ ushort f2h(float x) {
    _Float16 h = (_Float16)x;
    return __builtin_bit_cast(ushort, h);
}

// ---------------------------------------------------------------------------
// Fused prep kernel (round 7): split x + transpose qkv_w + transpose proj_w.
// ---------------------------------------------------------------------------
__device__ __forceinline__ void tsplit_tile(
    const float* __restrict__ W, ushort* __restrict__ T, int K, int N,
    int n0, int k0, float (*s)[33], int tid)
{
    {
        int tn = tid & 31, tk = tid >> 5;
        #pragma unroll
        for (int i = 0; i < 4; ++i)
            s[tk + i * 8][tn] = W[(size_t)(k0 + tk + i * 8) * N + n0 + tn];
    }
    __syncthreads();
    {
        int tk = tid & 31, tn = tid >> 5;
        #pragma unroll
        for (int i = 0; i < 4; ++i)
            T[(size_t)(n0 + tn + i * 8) * K + k0 + tk] = f2h(s[tk][tn + i * 8]);
    }
}

__global__ __launch_bounds__(256) void prep_kernel(
    const float* __restrict__ x, ushort* __restrict__ a_hi,
    ushort* __restrict__ a_lo,
    const float* __restrict__ qkv_w, ushort* __restrict__ wT,
    const float* __restrict__ proj_w, ushort* __restrict__ pT)
{
    __shared__ float s[32][33];
    const int tid = threadIdx.x;
    const int id = blockIdx.x;

    if (id < 5120) {
        int i = id * 256 + tid;
        float4 v = ((const float4*)x)[i];
        ushort4 h, l;
        splitf16(v.x, h.x, l.x);
        splitf16(v.y, h.y, l.y);
        splitf16(v.z, h.z, l.z);
        splitf16(v.w, h.w, l.w);
        ((ushort4*)a_hi)[i] = h;
        ((ushort4*)a_lo)[i] = l;
    } else if (id < 9920) {
        int id2 = id - 5120;
        int n0 = (id2 % 120) * 32, k0 = (id2 / 120) * 32;
        tsplit_tile(qkv_w, wT, HIDDEN, 3 * HIDDEN, n0, k0, s, tid);
    } else {
        int id2 = id - 9920;
        int n0 = (id2 % 40) * 32, k0 = (id2 / 40) * 32;
        tsplit_tile(proj_w, pT, HIDDEN, HIDDEN, n0, k0, s, tid);
    }
}

// ---------------------------------------------------------------------------
// fp16x2 MFMA GEMM 128x128 v2 (proj GEMM): de-pessimized sync structure.
// Was: single buffer, 2 barriers/tile + full vmcnt drain between staging and
// compute (m97 disease). Now: double-buffered (48 KB, 3 blocks/CU), stage
// (t+1) issued FIRST each tile, frag ds_reads and 32 MFMAs left to the
// compiler's fine-grained lgkmcnt scheduling (no lgkmcnt(0)/sched_barrier
// pins), one vmcnt(0)+barrier per tile (loads are a full tile old -> free).
// Per-acc-element math order unchanged (al then ah, K ascending).
// ---------------------------------------------------------------------------
#define BM 128
#define BN 128
#define BK 32

__global__ __launch_bounds__(256) void gemm_f16x2_kernel(
    const ushort* __restrict__ Ahi, const ushort* __restrict__ Alo,
    const ushort* __restrict__ Bh,
    const float* __restrict__ bias, float* __restrict__ C,
    int M, int N, int K)
{
    __shared__ __align__(16) ushort lds[2 * 12288];   // 49152 B

    const int tid = threadIdx.x;
    const int wid = tid >> 6;
    const int lane = tid & 63;
    const int col0 = blockIdx.x * BN;
    const int row0 = blockIdx.y * BM;
    const int wy = wid >> 1, wx = wid & 1;
    const int lrow = lane >> 2;
    const int lchunk = lane & 3;
    const int q = lane >> 4;
    const int r = lane & 15;

    // 24 segments (3 tiles x 8), 6 per wave — precomputed base addressing
    const ushort* gsrc[6];
    int ldst[6];
    #pragma unroll
    for (int i = 0; i < 6; ++i) {
        int s = wid + i * 4;
        int tile = s >> 3, t = s & 7;
        const ushort* src = (tile == 0) ? Ahi : (tile == 1) ? Alo : Bh;
        int srow = (tile < 2) ? row0 : col0;
        gsrc[i] = src + (size_t)(srow + t * 16 + lrow) * K + lchunk * 8;
        ldst[i] = tile * 4096 + t * 512 + lane * 8;
    }

    const int NT = K / BK;

    // prologue: stage tile 0 -> buf0
    #pragma unroll
    for (int i = 0; i < 6; ++i)
        __builtin_amdgcn_global_load_lds((const AS1 unsigned int*)(gsrc[i]),
            (AS3 unsigned int*)(lds + ldst[i]), 16, 0, 0);
    asm volatile("s_waitcnt vmcnt(0)" ::: "memory");
    __builtin_amdgcn_s_barrier();

    f32x4 acc[4][4] = {};
    int cb = 0;

    for (int t = 0; t < NT; ++t) {
        const ushort* base = lds + cb;
        ushort* nbuf = lds + (12288 - cb);
        if (t + 1 < NT) {
            const int ko = (t + 1) * BK;
            #pragma unroll
            for (int i = 0; i < 6; ++i)
                __builtin_amdgcn_global_load_lds((const AS1 unsigned int*)(gsrc[i] + ko),
                    (AS3 unsigned int*)(nbuf + ldst[i]), 16, 0, 0);
        }

        f16x8 ah[4], al[4], bf[4];
        #pragma unroll
        for (int i = 0; i < 4; ++i) {
            int arow = wy * 64 + i * 16 + r;
            ah[i] = *(const f16x8*)(base + 0 * 4096 + arow * 32 + q * 8);
            al[i] = *(const f16x8*)(base + 1 * 4096 + arow * 32 + q * 8);
            int brow = wx * 64 + i * 16 + r;
            bf[i] = *(const f16x8*)(base + 2 * 4096 + brow * 32 + q * 8);
        }
        #pragma unroll
        for (int i = 0; i < 4; ++i) {
            #pragma unroll
            for (int j = 0; j < 4; ++j) {
                acc[i][j] = __builtin_amdgcn_mfma_f32_16x16x32_f16(al[i], bf[j], acc[i][j], 0, 0, 0);
                acc[i][j] = __builtin_amdgcn_mfma_f32_16x16x32_f16(ah[i], bf[j], acc[i][j], 0, 0, 0);
            }
        }

        asm volatile("s_waitcnt vmcnt(0)" ::: "memory");
        __builtin_amdgcn_s_barrier();
        cb = 12288 - cb;
    }

    #pragma unroll
    for (int i = 0; i < 4; ++i) {
        #pragma unroll
        for (int j = 0; j < 4; ++j) {
            int col = col0 + wx * 64 + j * 16 + r;
            float b = bias[col];
            #pragma unroll
            for (int v = 0; v < 4; ++v) {
                int row = row0 + wy * 64 + i * 16 + q * 4 + v;
                C[(size_t)row * N + col] = acc[i][j][v] + b;
            }
        }
    }
}

// ---------------------------------------------------------------------------
// 256x128 8-wave fp16x2 GEMM v4 (QKV GEMM): phase-fused de-pessimized sync.
// v2's 4 phases pinned lgkmcnt(0)+sched_barrier(0) between ds_reads and
// MFMAs, with 4 barriers/tile -> LDS port and MFMA pipe fully serialized
// (2304 + 2483 cyc/CU/tile = measured 82 us). v4: stage(t+1) first, all 12
// frag reads + all 32 MFMAs compiler-scheduled (hipcc emits fine-grained
// lgkmcnt interleave — m97 evidence), ONE vmcnt(0)+barrier per tile (the
// drained loads are a full tile old -> free). Buffer race analysis: tile t
// reads buf A, stages into buf B; swap happens only after the barrier at
// which all waves finished reading A and all staging into B landed.
// Per-acc-element math order unchanged -> bit-identical.
// ---------------------------------------------------------------------------
__global__ __launch_bounds__(512, 4) void gemm_f16x2_256x128_kernel(
    const ushort* __restrict__ Ahi, const ushort* __restrict__ Alo,
    const ushort* __restrict__ Bh,
    const float* __restrict__ bias, float* __restrict__ C,
    int M, int N, int K, int nbx)
{
    __shared__ __align__(16) ushort lds[2 * 20480];   // 81920 B

    const int tid = threadIdx.x;
    const int wid = tid >> 6;
    const int lane = tid & 63;
    const int q = lane >> 4, r = lane & 15;
    const int wr = wid >> 1;      // 0..3: 64-row band
    const int wc = wid & 1;       // 0..1: 64-col band

    // T1: XCD-aware block swizzle (valid: grid % 8 == 0)
    int id = blockIdx.x;
    {
        int nwg = gridDim.x;
        if ((nwg & 7) == 0) {
            int c = nwg >> 3;
            id = (id & 7) * c + (id >> 3);
        }
    }
    const int row0 = (id / nbx) * 256;
    const int col0 = (id % nbx) * 128;

    // --- staging: 5 global_load_lds per K-tile per wave ---
    const ushort* gsrc[5];
    int ldst[5];
    #pragma unroll
    for (int j = 0; j < 5; ++j) {
        if (j < 4) {
            int p = j >> 1;
            int rloc = wid * 32 + (j & 1) * 16 + (lane >> 2);
            int sl = (lane & 3) ^ ((rloc >> 1) & 3);
            const ushort* base = p ? Alo : Ahi;
            gsrc[j] = base + (size_t)(row0 + rloc) * K + sl * 8;
            ldst[j] = p * 8192 + (wid * 32 + (j & 1) * 16) * 32 + lane * 8;
        } else {
            int rloc = wid * 16 + (lane >> 2);
            int sl = (lane & 3) ^ ((rloc >> 1) & 3);
            gsrc[4] = Bh + (size_t)(col0 + rloc) * K + sl * 8;
            ldst[4] = 16384 + wid * 512 + lane * 8;
        }
    }

    const int NT = K / 32;

    // prologue: stage tile 0 -> buf0
    #pragma unroll
    for (int j = 0; j < 5; ++j)
        __builtin_amdgcn_global_load_lds((const AS1 unsigned int*)(gsrc[j]),
            (AS3 unsigned int*)(lds + ldst[j]), 16, 0, 0);
    asm volatile("s_waitcnt vmcnt(0)" ::: "memory");
    __builtin_amdgcn_s_barrier();

    const int soff = (q ^ ((r >> 1) & 3)) * 8;
    const int arow0 = wr * 64 + r;     // + m*16
    const int brow0 = wc * 64 + r;     // + n*16

    f32x4 acc[4][4] = {};

    int cb = 0;
    for (int t = 0; t < NT; ++t) {
        const ushort* A0 = lds + cb;
        const ushort* A1 = lds + cb + 8192;
        const ushort* Bp = lds + cb + 16384;
        ushort* nbuf = lds + (20480 - cb);

        // issue next tile's staging first (maximum latency hiding)
        if (t + 1 < NT) {
            const int ko = (t + 1) * 32;
            #pragma unroll
            for (int j = 0; j < 5; ++j)
                __builtin_amdgcn_global_load_lds((const AS1 unsigned int*)(gsrc[j] + ko),
                    (AS3 unsigned int*)(nbuf + ldst[j]), 16, 0, 0);
        }

        // all frag reads + all MFMAs, compiler-scheduled (no pins):
        // hipcc interleaves ds_reads under MFMAs with counted lgkmcnt.
        f16x8 ah[4], al[4], bf[4];
        #pragma unroll
        for (int m = 0; m < 4; ++m) {
            int ro = (arow0 + m * 16) * 32 + soff;
            ah[m] = *(const f16x8*)(A0 + ro);
            al[m] = *(const f16x8*)(A1 + ro);
        }
        #pragma unroll
        for (int n = 0; n < 4; ++n)
            bf[n] = *(const f16x8*)(Bp + (brow0 + n * 16) * 32 + soff);

        __builtin_amdgcn_s_setprio(1);
        #pragma unroll
        for (int m = 0; m < 4; ++m) {
            #pragma unroll
            for (int n = 0; n < 4; ++n) {
                acc[m][n] = __builtin_amdgcn_mfma_f32_16x16x32_f16(al[m], bf[n], acc[m][n], 0, 0, 0);
                acc[m][n] = __builtin_amdgcn_mfma_f32_16x16x32_f16(ah[m], bf[n], acc[m][n], 0, 0, 0);
            }
        }
        __builtin_amdgcn_s_setprio(0);

        // single sync point per tile: staged loads are a full tile old
        asm volatile("s_waitcnt vmcnt(0)" ::: "memory");
        __builtin_amdgcn_s_barrier();
        cb = 20480 - cb;
    }

    // epilogue: bias + store
    #pragma unroll
    for (int m = 0; m < 4; ++m) {
        #pragma unroll
        for (int n = 0; n < 4; ++n) {
            int col = col0 + wc * 64 + n * 16 + r;
            float b = bias[col];
            #pragma unroll
            for (int v = 0; v < 4; ++v) {
                int row = row0 + wr * 64 + m * 16 + q * 4 + v;
                C[(size_t)row * N + col] = acc[m][n][v] + b;
            }
        }
    }
}

// ---------------------------------------------------------------------------
// RoPE + scale + fp16 convert + head-major relayout. (unchanged)
// ---------------------------------------------------------------------------
__global__ __launch_bounds__(256) void rope_split_kernel(
    const float* __restrict__ qkv, const float* __restrict__ cos_t,
    const float* __restrict__ sin_t,
    ushort* __restrict__ qf, ushort* __restrict__ kf,
    ushort* __restrict__ vt)
{
    __shared__ float s_v[64][84];
    const int tid = threadIdx.x;
    const int b = blockIdx.z, h = blockIdx.y;
    const int n0 = blockIdx.x * 64;
    const int bh = b * HEADS + h;

    // V tile -> LDS (coalesced float4 loads)
    #pragma unroll
    for (int i = 0; i < 5; ++i) {
        int u = tid + i * 256;
        int n = u / 20, c = u % 20;
        const float* src = qkv + (size_t)(b * NN + n0 + n) * 3840 + 2 * HIDDEN + h * HD + c * 4;
        *(float4*)(&s_v[n][c * 4]) = *(const float4*)src;
    }

    // q,k RoPE + fp16: 640 units, each = (token n, 4-wide d group in [0,40))
    for (int u = tid; u < 640; u += 256) {
        int n = u / 10, p = u % 10;
        int d = p * 4;
        int ng = n0 + n;
        size_t rowb = (size_t)(b * NN + ng) * 3840;
        float4 c0 = *(const float4*)(cos_t + ng * HD + d);
        float4 c1 = *(const float4*)(cos_t + ng * HD + d + HALF);
        float4 s0 = *(const float4*)(sin_t + ng * HD + d);
        float4 s1 = *(const float4*)(sin_t + ng * HD + d + HALF);
        size_t qo = ((size_t)bh * NN + ng) * 96;
        // q (scaled by QSCALE so scores are in log2 domain)
        {
            float4 x0 = *(const float4*)(qkv + rowb + h * HD + d);
            float4 x1 = *(const float4*)(qkv + rowb + h * HD + d + HALF);
            ushort4 h4a, h4b;
            h4a.x = f2h((x0.x * c0.x - x1.x * s0.x) * QSCALE);
            h4a.y = f2h((x0.y * c0.y - x1.y * s0.y) * QSCALE);
            h4a.z = f2h((x0.z * c0.z - x1.z * s0.z) * QSCALE);
            h4a.w = f2h((x0.w * c0.w - x1.w * s0.w) * QSCALE);
            h4b.x = f2h((x1.x * c1.x + x0.x * s1.x) * QSCALE);
            h4b.y = f2h((x1.y * c1.y + x0.y * s1.y) * QSCALE);
            h4b.z = f2h((x1.z * c1.z + x0.z * s1.z) * QSCALE);
            h4b.w = f2h((x1.w * c1.w + x0.w * s1.w) * QSCALE);
            *(ushort4*)(qf + qo + d) = h4a;
            *(ushort4*)(qf + qo + d + HALF) = h4b;
        }
        // k (unscaled)
        {
            float4 x0 = *(const float4*)(qkv + rowb + HIDDEN + h * HD + d);
            float4 x1 = *(const float4*)(qkv + rowb + HIDDEN + h * HD + d + HALF);
            ushort4 h4a, h4b;
            h4a.x = f2h(x0.x * c0.x - x1.x * s0.x);
            h4a.y = f2h(x0.y * c0.y - x1.y * s0.y);
            h4a.z = f2h(x0.z * c0.z - x1.z * s0.z);
            h4a.w = f2h(x0.w * c0.w - x1.w * s0.w);
            h4b.x = f2h(x1.x * c1.x + x0.x * s1.x);
            h4b.y = f2h(x1.y * c1.y + x0.y * s1.y);
            h4b.z = f2h(x1.z * c1.z + x0.z * s1.z);
            h4b.w = f2h(x1.w * c1.w + x0.w * s1.w);
            *(ushort4*)(kf + qo + d) = h4a;
            *(ushort4*)(kf + qo + d + HALF) = h4b;
        }
    }

    // zero the d=80..95 pad for q and k. 256 units: which(1b) x n(6b) x part(1b)
    {
        int which = tid >> 7;
        int u = tid & 127;
        int n = u >> 1, part = u & 1;
        size_t o = ((size_t)bh * NN + n0 + n) * 96 + 80 + part * 8;
        uint4 z = {0u, 0u, 0u, 0u};
        if (which == 0) *(uint4*)(qf + o) = z;
        else            *(uint4*)(kf + o) = z;
    }
    __syncthreads();

    // V^T write (fp16): unit = (d, 16-token chunk)
    for (int u = tid; u < 320; u += 256) {
        int d = u >> 2, nc = u & 3;
        ushort hs[16];
        #pragma unroll
        for (int kk = 0; kk < 16; ++kk)
            hs[kk] = f2h(s_v[nc * 16 + kk][d]);
        size_t o = ((size_t)bh * HD + d) * NN + n0 + nc * 16;
        uint4 w0, w1;
        w0.x = (uint)hs[0] | ((uint)hs[1] << 16);
        w0.y = (uint)hs[2] | ((uint)hs[3] << 16);
        w0.z = (uint)hs[4] | ((uint)hs[5] << 16);
        w0.w = (uint)hs[6] | ((uint)hs[7] << 16);
        w1.x = (uint)hs[8] | ((uint)hs[9] << 16);
        w1.y = (uint)hs[10] | ((uint)hs[11] << 16);
        w1.z = (uint)hs[12] | ((uint)hs[13] << 16);
        w1.w = (uint)hs[14] | ((uint)hs[15] << 16);
        *(uint4*)(vt + o) = w0;
        *(uint4*)(vt + o + 8) = w1;
    }
}

// ---------------------------------------------------------------------------
// MFMA flash attention v6 (measured best ~82 us; unchanged)
// ---------------------------------------------------------------------------
__global__ __launch_bounds__(512, 4) void attn_mfma_kernel(
    const ushort* __restrict__ qf, const ushort* __restrict__ kf,
    const ushort* __restrict__ vt,
    ushort* __restrict__ ao_hi, ushort* __restrict__ ao_lo)
{
    __shared__ __align__(16) ushort lds[34816];   // 69632 B
    _Float16* p_s = (_Float16*)(lds + 26624);

    const int tid = threadIdx.x;
    const int wave = tid >> 6, lane = tid & 63;
    const int quad = lane >> 4, r = lane & 15;
    const int b = blockIdx.z, h = blockIdx.y;
    const int bh = b * HEADS + h;
    const int q0 = blockIdx.x * 128;

    const size_t kb = (size_t)bh * NN * 96;
    const size_t vb = (size_t)bh * HD * NN;

    const ushort* gptr[4];
    int ldso[4];
    #pragma unroll
    for (int i = 0; i < 4; ++i) {
        int s = wave + i * 8;
        if (s < 16) {
            int row = s * 4 + (lane >> 4);
            int t = lane & 15;
            int g = t ^ (row & 7);
            if (g >= 12) g = 0;
            gptr[i] = kf + kb + (size_t)row * 96 + g * 8;
            ldso[i] = s * 512 + lane * 8;
        } else if (s < 26) {
            int ts = s - 16;
            gptr[i] = vt + vb + (size_t)(ts * 8 + (lane >> 3)) * NN
                      + (size_t)(((lane & 7) ^ (lane >> 3)) * 8);
            ldso[i] = 8192 + ts * 512 + lane * 8;
        } else {
            gptr[i] = nullptr;
            ldso[i] = 0;
        }
    }

    f16x8 qfr[3];
    #pragma unroll
    for (int c = 0; c < 3; ++c) {
        size_t o = ((size_t)bh * NN + q0 + wave * 16 + r) * 96 + c * 32 + quad * 8;
        qfr[c] = *(const f16x8*)(qf + o);
    }

    f32x4 oacc[5] = {};
    float l_part[4] = {};

    #pragma unroll
    for (int i = 0; i < 4; ++i) {
        int s = wave + i * 8;
        if (s < 26) {
            __builtin_amdgcn_global_load_lds((const AS1 unsigned int*)gptr[i],
                (AS3 unsigned int*)(lds + ldso[i]), 16, 0, 0);
            gptr[i] += (s < 16) ? 6144 : 64;
        }
    }
    asm volatile("s_waitcnt vmcnt(0)" ::: "memory");
    __builtin_amdgcn_s_barrier();

    int cur = 0;
    for (int j0 = 0; j0 < NN; j0 += 64) {
        const int nxt = 13312 - cur;
        if (j0 + 64 < NN) {
            #pragma unroll
            for (int i = 0; i < 4; ++i) {
                int s = wave + i * 8;
                if (s < 26) {
                    __builtin_amdgcn_global_load_lds((const AS1 unsigned int*)gptr[i],
                        (AS3 unsigned int*)(lds + nxt + ldso[i]), 16, 0, 0);
                    gptr[i] += (s < 16) ? 6144 : 64;
                }
            }
        }

        const ushort* k_s = lds + cur;
        const _Float16* v_s = (const _Float16*)(lds + cur + 8192);

        f32x4 sc[4] = {};
        __builtin_amdgcn_s_setprio(1);
        #pragma unroll
        for (int jt = 0; jt < 4; ++jt) {
            f16x8 kbf[3];
            int j = jt * 16 + r;
            #pragma unroll
            for (int c = 0; c < 3; ++c) {
                int ch = (c * 4 + quad) ^ (r & 7);
                kbf[c] = *(const f16x8*)(k_s + j * 128 + ch * 8);
            }
            #pragma unroll
            for (int c = 0; c < 3; ++c)
                sc[jt] = __builtin_amdgcn_mfma_f32_16x16x32_f16(qfr[c], kbf[c], sc[jt], 0, 0, 0);
        }
        __builtin_amdgcn_s_setprio(0);

        #pragma unroll
        for (int v = 0; v < 4; ++v) {
            float ps = 0.0f;
            #pragma unroll
            for (int jt = 0; jt < 4; ++jt) {
                float p = __builtin_amdgcn_exp2f(sc[jt][v]);
                sc[jt][v] = p;
                ps += p;
            }
            l_part[v] += ps;
        }
        {
            int rowbase = wave * 16 + quad * 4;
            #pragma unroll
            for (int jt = 0; jt < 4; ++jt) {
                int bks = (jt * 2 + (r >> 3)) ^ (quad << 1);
                #pragma unroll
                for (int v = 0; v < 4; ++v)
                    p_s[(rowbase + v) * 64 + bks * 8 + (r & 7)] = (_Float16)sc[jt][v];
            }
        }

        f16x8 pa[2];
        #pragma unroll
        for (int cc = 0; cc < 2; ++cc) {
            int rowp = wave * 16 + r;
            int bks = (cc * 4 + quad) ^ (((r >> 2) & 3) << 1);
            pa[cc] = *(const f16x8*)(p_s + rowp * 64 + bks * 8);
        }

        __builtin_amdgcn_s_setprio(1);
        #pragma unroll
        for (int dt = 0; dt < 5; ++dt)
            #pragma unroll
            for (int cc = 0; cc < 2; ++cc) {
                int ck = (cc * 4 + quad) ^ (r & 7);
                f16x8 vbf = *(const f16x8*)(v_s + (dt * 16 + r) * 64 + ck * 8);
                oacc[dt] = __builtin_amdgcn_mfma_f32_16x16x32_f16(pa[cc], vbf, oacc[dt], 0, 0, 0);
            }
        __builtin_amdgcn_s_setprio(0);

        asm volatile("s_waitcnt vmcnt(0)" ::: "memory");
        __builtin_amdgcn_s_barrier();
        cur = nxt;
    }

    float inv_l[4];
    #pragma unroll
    for (int v = 0; v < 4; ++v) {
        float l = l_part[v];
        l += __shfl_xor(l, 1);
        l += __shfl_xor(l, 2);
        l += __shfl_xor(l, 4);
        l += __shfl_xor(l, 8);
        inv_l[v] = 1.0f / l;
    }

    __syncthreads();
    #pragma unroll
    for (int v = 0; v < 4; ++v) {
        int row = wave * 16 + quad * 4 + v;
        #pragma unroll
        for (int dt = 0; dt < 5; ++dt) {
            float o = oacc[dt][v] * inv_l[v];
            ushort hh, ll;
            splitf16(o, hh, ll);
            lds[row * 80 + dt * 16 + r] = hh;
            lds[10240 + row * 80 + dt * 16 + r] = ll;
        }
    }
    __syncthreads();
    {
        size_t gbase = ((size_t)b * NN + q0) * HIDDEN + h * HD;
        #pragma unroll
        for (int i = 0; i < 5; ++i) {
            int u = tid + i * 512;            // 0..2559
            int plane = u / 1280, idx = u % 1280;
            int row = idx / 10, part = idx % 10;
            uint4 w = *(const uint4*)(lds + plane * 10240 + idx * 8);
            ushort* dst = (plane ? ao_lo : ao_hi) + gbase + (size_t)row * HIDDEN + part * 8;
            *(uint4*)dst = w;
        }
    }
}

// ---------------------------------------------------------------------------
extern "C" void kernel_launch(void* const* d_in, const int* in_sizes, int n_in,
                              void* d_out, int out_size, void* d_ws, size_t ws_size,
                              hipStream_t stream)
{
    const float* x      = (const float*)d_in[0];
    const float* cos_t  = (const float*)d_in[1];
    const float* sin_t  = (const float*)d_in[2];
    const float* qkv_w  = (const float*)d_in[3];
    const float* qkv_b  = (const float*)d_in[4];
    const float* proj_w = (const float*)d_in[5];
    const float* proj_b = (const float*)d_in[6];
    float* out = (float*)d_out;

    char* ws = (char*)d_ws;
    // layout (bytes), phase-based reuse:
    //   [0, 62914560)           qkv fp32 (gemm1 out; dead after rope_split)
    //       -> ao_hi @0 (10485760), ao_lo @10485760 (attn out, fp16 hi/lo)
    //   [62914560, 72744960)    wT fp16 (qkv_w^T); after gemm1:
    //       -> vt fp16 @62914560 (10485760, ends 73400320)
    //   [82575360, 103546880)   x split fp16 hi/lo (gemm1 A); after gemm1:
    //       -> qf @83886080 (12582912), kf @96468992 (ends 109051904)
    //   [109051904, 112328704)  pT fp16 (proj_w^T)
    float*  qkv   = (float*)ws;
    ushort* ao_hi = (ushort*)ws;
    ushort* ao_lo = (ushort*)(ws + 10485760);
    ushort* wT    = (ushort*)(ws + 62914560);
    ushort* vt    = (ushort*)(ws + 62914560);
    ushort* a_hi  = (ushort*)(ws + 82575360);
    ushort* a_lo  = (ushort*)(ws + 93061120);
    ushort* q_f   = (ushort*)(ws + 83886080);
    ushort* k_f   = (ushort*)(ws + 96468992);
    ushort* pT    = (ushort*)(ws + 109051904);

    // 1) fused prep: split x -> hi/lo, transpose qkv_w -> wT, proj_w -> pT
    prep_kernel<<<dim3(11520), 256, 0, stream>>>(
        x, a_hi, a_lo, qkv_w, wT, proj_w, pT);

    // 2) qkv = x @ qkv_w + qkv_b   (256x128 v4, phase-fused 1-barrier/tile)
    gemm_f16x2_256x128_kernel<<<dim3((MROWS / 256) * (3 * HIDDEN / 128)), 512, 0, stream>>>(
        a_hi, a_lo, wT, qkv_b, qkv, MROWS, 3 * HIDDEN, HIDDEN, 3 * HIDDEN / 128);

    // 3) RoPE + fp16 relayout (overwrites wT and x-split regions — both dead)
    rope_split_kernel<<<dim3(NN / 64, HEADS, BB), 256, 0, stream>>>(
        qkv, cos_t, sin_t, q_f, k_f, vt);

    // 4) MFMA flash attention v6 (8 waves, LDS-staged)
    attn_mfma_kernel<<<dim3(NN / 128, HEADS, BB), 512, 0, stream>>>(
        q_f, k_f, vt, ao_hi, ao_lo);

    // 5) out = attn_out @ proj_w + proj_b  (128^2 v2, double-buffered
    //    1-barrier/tile, 320 wgs)
    gemm_f16x2_kernel<<<dim3(HIDDEN / BN, MROWS / BM), 256, 0, stream>>>(
        ao_hi, ao_lo, pT, proj_b, out, MROWS, HIDDEN, HIDDEN);
}

// Round 10
// 306.094 us; speedup vs baseline: 1.0324x; 1.0324x over previous
//
#include <hip/hip_runtime.h>
#include <hip/hip_bf16.h>
#include <math.h>

#define HIDDEN 1280
#define HEADS 16
#define HD 80           // head dim
#define HALF 40
#define BB 2
#define NN 2048
#define MROWS (BB * NN) // 4096
// 1/sqrt(80) * log2(e): scores come out in log2 domain -> exp2 directly
#define QSCALE ((float)(0.11180339887498949 * 1.4426950408889634))

typedef __attribute__((ext_vector_type(8))) _Float16 f16x8;
typedef __attribute__((ext_vector_type(4))) float f32x4;

#define AS1 __attribute__((address_space(1)))
#define AS3 __attribute__((address_space(3)))

// Split fp32 into fp16 hi + fp16 lo (hi+lo carries ~22 mantissa bits).
__device__ __forceinline__ void splitf16(float x, ushort& hi, ushort& lo) {
    _Float16 h = (_Float16)x;
    _Float16 l = (_Float16)(x - (float)h);
    hi = __builtin_bit_cast(ushort, h);
    lo = __builtin_bit_cast(ushort, l);
}

__device__ __forceinline__ ushort f2h(float x) {
    _Float16 h = (_Float16)x;
    return __builtin_bit_cast(ushort, h);
}

// ---------------------------------------------------------------------------
// Fused prep kernel: split x + transpose qkv_w + transpose proj_w.
// ---------------------------------------------------------------------------
__device__ __forceinline__ void tsplit_tile(
    const float* __restrict__ W, ushort* __restrict__ T, int K, int N,
    int n0, int k0, float (*s)[33], int tid)
{
    {
        int tn = tid & 31, tk = tid >> 5;
        #pragma unroll
        for (int i = 0; i < 4; ++i)
            s[tk + i * 8][tn] = W[(size_t)(k0 + tk + i * 8) * N + n0 + tn];
    }
    __syncthreads();
    {
        int tk = tid & 31, tn = tid >> 5;
        #pragma unroll
        for (int i = 0; i < 4; ++i)
            T[(size_t)(n0 + tn + i * 8) * K + k0 + tk] = f2h(s[tk][tn + i * 8]);
    }
}

__global__ __launch_bounds__(256) void prep_kernel(
    const float* __restrict__ x, ushort* __restrict__ a_hi,
    ushort* __restrict__ a_lo,
    const float* __restrict__ qkv_w, ushort* __restrict__ wT,
    const float* __restrict__ proj_w, ushort* __restrict__ pT)
{
    __shared__ float s[32][33];
    const int tid = threadIdx.x;
    const int id = blockIdx.x;

    if (id < 5120) {
        int i = id * 256 + tid;
        float4 v = ((const float4*)x)[i];
        ushort4 h, l;
        splitf16(v.x, h.x, l.x);
        splitf16(v.y, h.y, l.y);
        splitf16(v.z, h.z, l.z);
        splitf16(v.w, h.w, l.w);
        ((ushort4*)a_hi)[i] = h;
        ((ushort4*)a_lo)[i] = l;
    } else if (id < 9920) {
        int id2 = id - 5120;
        int n0 = (id2 % 120) * 32, k0 = (id2 / 120) * 32;
        tsplit_tile(qkv_w, wT, HIDDEN, 3 * HIDDEN, n0, k0, s, tid);
    } else {
        int id2 = id - 9920;
        int n0 = (id2 % 40) * 32, k0 = (id2 / 40) * 32;
        tsplit_tile(proj_w, pT, HIDDEN, HIDDEN, n0, k0, s, tid);
    }
}

// ---------------------------------------------------------------------------
// fp16x2 MFMA GEMM 128x128 v2 (proj GEMM) — round-8 WINNER (kept): double-
// buffered (48 KB, 3 blocks/CU), stage(t+1) issued first, frag ds_reads and
// 32 MFMAs compiler-scheduled (no pins), one vmcnt(0)+barrier per tile.
// Measured delta round 7->8: proj GEMM ~39 -> ~27 us (total-flat decompose).
// At 4 waves/block low occupancy the compiler's fine-grained lgkmcnt
// interleave wins; no phase-barrier role-split needed (unlike 8-wave 256x128,
// where the same transform REGRESSED — structure-conditional, see below).
// ---------------------------------------------------------------------------
#define BM 128
#define BN 128
#define BK 32

__global__ __launch_bounds__(256) void gemm_f16x2_kernel(
    const ushort* __restrict__ Ahi, const ushort* __restrict__ Alo,
    const ushort* __restrict__ Bh,
    const float* __restrict__ bias, float* __restrict__ C,
    int M, int N, int K)
{
    __shared__ __align__(16) ushort lds[2 * 12288];   // 49152 B

    const int tid = threadIdx.x;
    const int wid = tid >> 6;
    const int lane = tid & 63;
    const int col0 = blockIdx.x * BN;
    const int row0 = blockIdx.y * BM;
    const int wy = wid >> 1, wx = wid & 1;
    const int lrow = lane >> 2;
    const int lchunk = lane & 3;
    const int q = lane >> 4;
    const int r = lane & 15;

    // 24 segments (3 tiles x 8), 6 per wave — precomputed base addressing
    const ushort* gsrc[6];
    int ldst[6];
    #pragma unroll
    for (int i = 0; i < 6; ++i) {
        int s = wid + i * 4;
        int tile = s >> 3, t = s & 7;
        const ushort* src = (tile == 0) ? Ahi : (tile == 1) ? Alo : Bh;
        int srow = (tile < 2) ? row0 : col0;
        gsrc[i] = src + (size_t)(srow + t * 16 + lrow) * K + lchunk * 8;
        ldst[i] = tile * 4096 + t * 512 + lane * 8;
    }

    const int NT = K / BK;

    // prologue: stage tile 0 -> buf0
    #pragma unroll
    for (int i = 0; i < 6; ++i)
        __builtin_amdgcn_global_load_lds((const AS1 unsigned int*)(gsrc[i]),
            (AS3 unsigned int*)(lds + ldst[i]), 16, 0, 0);
    asm volatile("s_waitcnt vmcnt(0)" ::: "memory");
    __builtin_amdgcn_s_barrier();

    f32x4 acc[4][4] = {};
    int cb = 0;

    for (int t = 0; t < NT; ++t) {
        const ushort* base = lds + cb;
        ushort* nbuf = lds + (12288 - cb);
        if (t + 1 < NT) {
            const int ko = (t + 1) * BK;
            #pragma unroll
            for (int i = 0; i < 6; ++i)
                __builtin_amdgcn_global_load_lds((const AS1 unsigned int*)(gsrc[i] + ko),
                    (AS3 unsigned int*)(nbuf + ldst[i]), 16, 0, 0);
        }

        f16x8 ah[4], al[4], bf[4];
        #pragma unroll
        for (int i = 0; i < 4; ++i) {
            int arow = wy * 64 + i * 16 + r;
            ah[i] = *(const f16x8*)(base + 0 * 4096 + arow * 32 + q * 8);
            al[i] = *(const f16x8*)(base + 1 * 4096 + arow * 32 + q * 8);
            int brow = wx * 64 + i * 16 + r;
            bf[i] = *(const f16x8*)(base + 2 * 4096 + brow * 32 + q * 8);
        }
        #pragma unroll
        for (int i = 0; i < 4; ++i) {
            #pragma unroll
            for (int j = 0; j < 4; ++j) {
                acc[i][j] = __builtin_amdgcn_mfma_f32_16x16x32_f16(al[i], bf[j], acc[i][j], 0, 0, 0);
                acc[i][j] = __builtin_amdgcn_mfma_f32_16x16x32_f16(ah[i], bf[j], acc[i][j], 0, 0, 0);
            }
        }

        asm volatile("s_waitcnt vmcnt(0)" ::: "memory");
        __builtin_amdgcn_s_barrier();
        cb = 12288 - cb;
    }

    #pragma unroll
    for (int i = 0; i < 4; ++i) {
        #pragma unroll
        for (int j = 0; j < 4; ++j) {
            int col = col0 + wx * 64 + j * 16 + r;
            float b = bias[col];
            #pragma unroll
            for (int v = 0; v < 4; ++v) {
                int row = row0 + wy * 64 + i * 16 + q * 4 + v;
                C[(size_t)row * N + col] = acc[i][j][v] + b;
            }
        }
    }
}

// ---------------------------------------------------------------------------
// 256x128 8-wave fp16x2 GEMM v2 (QKV GEMM) — REVERTED to the measured-best
// 4-phase structure (81.5-83 us, MfmaUtil 43%, 0 conflicts). Round 8's
// phase-fused v4 REGRESSED this kernel to 95 us (MfmaUtil 35, FETCH +23MB):
// at 8 waves/block the per-phase barriers + lgkmcnt pins provide the wave
// role-split (T3 mechanism) that keeps LDS port and MFMA pipe co-utilized;
// removing them made the waves lockstep. Structure-conditional — do not
// "de-pessimize" this kernel again.
// ---------------------------------------------------------------------------
__global__ __launch_bounds__(512, 4) void gemm_f16x2_256x128_kernel(
    const ushort* __restrict__ Ahi, const ushort* __restrict__ Alo,
    const ushort* __restrict__ Bh,
    const float* __restrict__ bias, float* __restrict__ C,
    int M, int N, int K, int nbx)
{
    __shared__ __align__(16) ushort lds[2 * 20480];   // 81920 B

    const int tid = threadIdx.x;
    const int wid = tid >> 6;
    const int lane = tid & 63;
    const int q = lane >> 4, r = lane & 15;
    const int wr = wid >> 1;      // 0..3: 64-row band
    const int wc = wid & 1;       // 0..1: 64-col band

    // T1: XCD-aware block swizzle (valid: grid % 8 == 0)
    int id = blockIdx.x;
    {
        int nwg = gridDim.x;
        if ((nwg & 7) == 0) {
            int c = nwg >> 3;
            id = (id & 7) * c + (id >> 3);
        }
    }
    const int row0 = (id / nbx) * 256;
    const int col0 = (id % nbx) * 128;

    // --- staging: 5 global_load_lds per K-tile per wave ---
    const ushort* gsrc[5];
    int ldst[5];
    #pragma unroll
    for (int j = 0; j < 5; ++j) {
        if (j < 4) {
            int p = j >> 1;
            int rloc = wid * 32 + (j & 1) * 16 + (lane >> 2);
            int sl = (lane & 3) ^ ((rloc >> 1) & 3);
            const ushort* base = p ? Alo : Ahi;
            gsrc[j] = base + (size_t)(row0 + rloc) * K + sl * 8;
            ldst[j] = p * 8192 + (wid * 32 + (j & 1) * 16) * 32 + lane * 8;
        } else {
            int rloc = wid * 16 + (lane >> 2);
            int sl = (lane & 3) ^ ((rloc >> 1) & 3);
            gsrc[4] = Bh + (size_t)(col0 + rloc) * K + sl * 8;
            ldst[4] = 16384 + wid * 512 + lane * 8;
        }
    }

    const int NT = K / 32;

    // prologue: stage tile 0 -> buf0
    #pragma unroll
    for (int j = 0; j < 5; ++j)
        __builtin_amdgcn_global_load_lds((const AS1 unsigned int*)(gsrc[j]),
            (AS3 unsigned int*)(lds + ldst[j]), 16, 0, 0);
    asm volatile("s_waitcnt vmcnt(0)" ::: "memory");
    __builtin_amdgcn_s_barrier();

    const int soff = (q ^ ((r >> 1) & 3)) * 8;
    const int arow0 = wr * 64 + r;     // + m*16
    const int brow0 = wc * 64 + r;     // + n*16

    f32x4 acc[4][4] = {};
    f16x8 ah[4], al[4], bf[2];

    int cb = 0;
    for (int t = 0; t < NT; ++t) {
        const ushort* A0 = lds + cb;
        const ushort* A1 = lds + cb + 8192;
        const ushort* Bp = lds + cb + 16384;
        ushort* nbuf = lds + (20480 - cb);
        const bool st = (t + 1 < NT);
        const int ko = (t + 1) * 32;

        // ---- phase 1: n0-1 ----
        #pragma unroll
        for (int m = 0; m < 4; ++m) {
            int ro = (arow0 + m * 16) * 32 + soff;
            ah[m] = *(const f16x8*)(A0 + ro);
            al[m] = *(const f16x8*)(A1 + ro);
        }
        #pragma unroll
        for (int n = 0; n < 2; ++n)
            bf[n] = *(const f16x8*)(Bp + (brow0 + n * 16) * 32 + soff);
        if (st) {
            __builtin_amdgcn_global_load_lds((const AS1 unsigned int*)(gsrc[0] + ko),
                (AS3 unsigned int*)(nbuf + ldst[0]), 16, 0, 0);
            __builtin_amdgcn_global_load_lds((const AS1 unsigned int*)(gsrc[1] + ko),
                (AS3 unsigned int*)(nbuf + ldst[1]), 16, 0, 0);
            __builtin_amdgcn_global_load_lds((const AS1 unsigned int*)(gsrc[2] + ko),
                (AS3 unsigned int*)(nbuf + ldst[2]), 16, 0, 0);
        }
        __builtin_amdgcn_s_barrier();
        asm volatile("s_waitcnt lgkmcnt(0)" ::: "memory");
        __builtin_amdgcn_sched_barrier(0);
        __builtin_amdgcn_s_setprio(1);
        #pragma unroll
        for (int m = 0; m < 4; ++m) {
            #pragma unroll
            for (int n = 0; n < 2; ++n) {
                acc[m][n] = __builtin_amdgcn_mfma_f32_16x16x32_f16(al[m], bf[n], acc[m][n], 0, 0, 0);
                acc[m][n] = __builtin_amdgcn_mfma_f32_16x16x32_f16(ah[m], bf[n], acc[m][n], 0, 0, 0);
            }
        }
        __builtin_amdgcn_s_setprio(0);
        __builtin_amdgcn_s_barrier();

        // ---- phase 2: n2-3 ----
        #pragma unroll
        for (int n = 0; n < 2; ++n)
            bf[n] = *(const f16x8*)(Bp + (brow0 + (n + 2) * 16) * 32 + soff);
        if (st) {
            __builtin_amdgcn_global_load_lds((const AS1 unsigned int*)(gsrc[3] + ko),
                (AS3 unsigned int*)(nbuf + ldst[3]), 16, 0, 0);
            __builtin_amdgcn_global_load_lds((const AS1 unsigned int*)(gsrc[4] + ko),
                (AS3 unsigned int*)(nbuf + ldst[4]), 16, 0, 0);
        }
        __builtin_amdgcn_s_barrier();
        asm volatile("s_waitcnt lgkmcnt(0)" ::: "memory");
        __builtin_amdgcn_sched_barrier(0);
        __builtin_amdgcn_s_setprio(1);
        #pragma unroll
        for (int m = 0; m < 4; ++m) {
            #pragma unroll
            for (int n = 0; n < 2; ++n) {
                acc[m][n + 2] = __builtin_amdgcn_mfma_f32_16x16x32_f16(al[m], bf[n], acc[m][n + 2], 0, 0, 0);
                acc[m][n + 2] = __builtin_amdgcn_mfma_f32_16x16x32_f16(ah[m], bf[n], acc[m][n + 2], 0, 0, 0);
            }
        }
        __builtin_amdgcn_s_setprio(0);
        asm volatile("s_waitcnt vmcnt(0)" ::: "memory");
        __builtin_amdgcn_s_barrier();
        cb = 20480 - cb;
    }

    // epilogue: bias + store
    #pragma unroll
    for (int m = 0; m < 4; ++m) {
        #pragma unroll
        for (int n = 0; n < 4; ++n) {
            int col = col0 + wc * 64 + n * 16 + r;
            float b = bias[col];
            #pragma unroll
            for (int v = 0; v < 4; ++v) {
                int row = row0 + wr * 64 + m * 16 + q * 4 + v;
                C[(size_t)row * N + col] = acc[m][n][v] + b;
            }
        }
    }
}

// ---------------------------------------------------------------------------
// RoPE + scale + fp16 convert + head-major relayout. (unchanged)
// ---------------------------------------------------------------------------
__global__ __launch_bounds__(256) void rope_split_kernel(
    const float* __restrict__ qkv, const float* __restrict__ cos_t,
    const float* __restrict__ sin_t,
    ushort* __restrict__ qf, ushort* __restrict__ kf,
    ushort* __restrict__ vt)
{
    __shared__ float s_v[64][84];
    const int tid = threadIdx.x;
    const int b = blockIdx.z, h = blockIdx.y;
    const int n0 = blockIdx.x * 64;
    const int bh = b * HEADS + h;

    // V tile -> LDS (coalesced float4 loads)
    #pragma unroll
    for (int i = 0; i < 5; ++i) {
        int u = tid + i * 256;
        int n = u / 20, c = u % 20;
        const float* src = qkv + (size_t)(b * NN + n0 + n) * 3840 + 2 * HIDDEN + h * HD + c * 4;
        *(float4*)(&s_v[n][c * 4]) = *(const float4*)src;
    }

    // q,k RoPE + fp16: 640 units, each = (token n, 4-wide d group in [0,40))
    for (int u = tid; u < 640; u += 256) {
        int n = u / 10, p = u % 10;
        int d = p * 4;
        int ng = n0 + n;
        size_t rowb = (size_t)(b * NN + ng) * 3840;
        float4 c0 = *(const float4*)(cos_t + ng * HD + d);
        float4 c1 = *(const float4*)(cos_t + ng * HD + d + HALF);
        float4 s0 = *(const float4*)(sin_t + ng * HD + d);
        float4 s1 = *(const float4*)(sin_t + ng * HD + d + HALF);
        size_t qo = ((size_t)bh * NN + ng) * 96;
        // q (scaled by QSCALE so scores are in log2 domain)
        {
            float4 x0 = *(const float4*)(qkv + rowb + h * HD + d);
            float4 x1 = *(const float4*)(qkv + rowb + h * HD + d + HALF);
            ushort4 h4a, h4b;
            h4a.x = f2h((x0.x * c0.x - x1.x * s0.x) * QSCALE);
            h4a.y = f2h((x0.y * c0.y - x1.y * s0.y) * QSCALE);
            h4a.z = f2h((x0.z * c0.z - x1.z * s0.z) * QSCALE);
            h4a.w = f2h((x0.w * c0.w - x1.w * s0.w) * QSCALE);
            h4b.x = f2h((x1.x * c1.x + x0.x * s1.x) * QSCALE);
            h4b.y = f2h((x1.y * c1.y + x0.y * s1.y) * QSCALE);
            h4b.z = f2h((x1.z * c1.z + x0.z * s1.z) * QSCALE);
            h4b.w = f2h((x1.w * c1.w + x0.w * s1.w) * QSCALE);
            *(ushort4*)(qf + qo + d) = h4a;
            *(ushort4*)(qf + qo + d + HALF) = h4b;
        }
        // k (unscaled)
        {
            float4 x0 = *(const float4*)(qkv + rowb + HIDDEN + h * HD + d);
            float4 x1 = *(const float4*)(qkv + rowb + HIDDEN + h * HD + d + HALF);
            ushort4 h4a, h4b;
            h4a.x = f2h(x0.x * c0.x - x1.x * s0.x);
            h4a.y = f2h(x0.y * c0.y - x1.y * s0.y);
            h4a.z = f2h(x0.z * c0.z - x1.z * s0.z);
            h4a.w = f2h(x0.w * c0.w - x1.w * s0.w);
            h4b.x = f2h(x1.x * c1.x + x0.x * s1.x);
            h4b.y = f2h(x1.y * c1.y + x0.y * s1.y);
            h4b.z = f2h(x1.z * c1.z + x0.z * s1.z);
            h4b.w = f2h(x1.w * c1.w + x0.w * s1.w);
            *(ushort4*)(kf + qo + d) = h4a;
            *(ushort4*)(kf + qo + d + HALF) = h4b;
        }
    }

    // zero the d=80..95 pad for q and k. 256 units: which(1b) x n(6b) x part(1b)
    {
        int which = tid >> 7;
        int u = tid & 127;
        int n = u >> 1, part = u & 1;
        size_t o = ((size_t)bh * NN + n0 + n) * 96 + 80 + part * 8;
        uint4 z = {0u, 0u, 0u, 0u};
        if (which == 0) *(uint4*)(qf + o) = z;
        else            *(uint4*)(kf + o) = z;
    }
    __syncthreads();

    // V^T write (fp16): unit = (d, 16-token chunk)
    for (int u = tid; u < 320; u += 256) {
        int d = u >> 2, nc = u & 3;
        ushort hs[16];
        #pragma unroll
        for (int kk = 0; kk < 16; ++kk)
            hs[kk] = f2h(s_v[nc * 16 + kk][d]);
        size_t o = ((size_t)bh * HD + d) * NN + n0 + nc * 16;
        uint4 w0, w1;
        w0.x = (uint)hs[0] | ((uint)hs[1] << 16);
        w0.y = (uint)hs[2] | ((uint)hs[3] << 16);
        w0.z = (uint)hs[4] | ((uint)hs[5] << 16);
        w0.w = (uint)hs[6] | ((uint)hs[7] << 16);
        w1.x = (uint)hs[8] | ((uint)hs[9] << 16);
        w1.y = (uint)hs[10] | ((uint)hs[11] << 16);
        w1.z = (uint)hs[12] | ((uint)hs[13] << 16);
        w1.w = (uint)hs[14] | ((uint)hs[15] << 16);
        *(uint4*)(vt + o) = w0;
        *(uint4*)(vt + o + 8) = w1;
    }
}

// ---------------------------------------------------------------------------
// MFMA flash attention v6 (measured best ~82 us; unchanged)
// ---------------------------------------------------------------------------
__global__ __launch_bounds__(512, 4) void attn_mfma_kernel(
    const ushort* __restrict__ qf, const ushort* __restrict__ kf,
    const ushort* __restrict__ vt,
    ushort* __restrict__ ao_hi, ushort* __restrict__ ao_lo)
{
    __shared__ __align__(16) ushort lds[34816];   // 69632 B
    _Float16* p_s = (_Float16*)(lds + 26624);

    const int tid = threadIdx.x;
    const int wave = tid >> 6, lane = tid & 63;
    const int quad = lane >> 4, r = lane & 15;
    const int b = blockIdx.z, h = blockIdx.y;
    const int bh = b * HEADS + h;
    const int q0 = blockIdx.x * 128;

    const size_t kb = (size_t)bh * NN * 96;
    const size_t vb = (size_t)bh * HD * NN;

    const ushort* gptr[4];
    int ldso[4];
    #pragma unroll
    for (int i = 0; i < 4; ++i) {
        int s = wave + i * 8;
        if (s < 16) {
            int row = s * 4 + (lane >> 4);
            int t = lane & 15;
            int g = t ^ (row & 7);
            if (g >= 12) g = 0;
            gptr[i] = kf + kb + (size_t)row * 96 + g * 8;
            ldso[i] = s * 512 + lane * 8;
        } else if (s < 26) {
            int ts = s - 16;
            gptr[i] = vt + vb + (size_t)(ts * 8 + (lane >> 3)) * NN
                      + (size_t)(((lane & 7) ^ (lane >> 3)) * 8);
            ldso[i] = 8192 + ts * 512 + lane * 8;
        } else {
            gptr[i] = nullptr;
            ldso[i] = 0;
        }
    }

    f16x8 qfr[3];
    #pragma unroll
    for (int c = 0; c < 3; ++c) {
        size_t o = ((size_t)bh * NN + q0 + wave * 16 + r) * 96 + c * 32 + quad * 8;
        qfr[c] = *(const f16x8*)(qf + o);
    }

    f32x4 oacc[5] = {};
    float l_part[4] = {};

    #pragma unroll
    for (int i = 0; i < 4; ++i) {
        int s = wave + i * 8;
        if (s < 26) {
            __builtin_amdgcn_global_load_lds((const AS1 unsigned int*)gptr[i],
                (AS3 unsigned int*)(lds + ldso[i]), 16, 0, 0);
            gptr[i] += (s < 16) ? 6144 : 64;
        }
    }
    asm volatile("s_waitcnt vmcnt(0)" ::: "memory");
    __builtin_amdgcn_s_barrier();

    int cur = 0;
    for (int j0 = 0; j0 < NN; j0 += 64) {
        const int nxt = 13312 - cur;
        if (j0 + 64 < NN) {
            #pragma unroll
            for (int i = 0; i < 4; ++i) {
                int s = wave + i * 8;
                if (s < 26) {
                    __builtin_amdgcn_global_load_lds((const AS1 unsigned int*)gptr[i],
                        (AS3 unsigned int*)(lds + nxt + ldso[i]), 16, 0, 0);
                    gptr[i] += (s < 16) ? 6144 : 64;
                }
            }
        }

        const ushort* k_s = lds + cur;
        const _Float16* v_s = (const _Float16*)(lds + cur + 8192);

        f32x4 sc[4] = {};
        __builtin_amdgcn_s_setprio(1);
        #pragma unroll
        for (int jt = 0; jt < 4; ++jt) {
            f16x8 kbf[3];
            int j = jt * 16 + r;
            #pragma unroll
            for (int c = 0; c < 3; ++c) {
                int ch = (c * 4 + quad) ^ (r & 7);
                kbf[c] = *(const f16x8*)(k_s + j * 128 + ch * 8);
            }
            #pragma unroll
            for (int c = 0; c < 3; ++c)
                sc[jt] = __builtin_amdgcn_mfma_f32_16x16x32_f16(qfr[c], kbf[c], sc[jt], 0, 0, 0);
        }
        __builtin_amdgcn_s_setprio(0);

        #pragma unroll
        for (int v = 0; v < 4; ++v) {
            float ps = 0.0f;
            #pragma unroll
            for (int jt = 0; jt < 4; ++jt) {
                float p = __builtin_amdgcn_exp2f(sc[jt][v]);
                sc[jt][v] = p;
                ps += p;
            }
            l_part[v] += ps;
        }
        {
            int rowbase = wave * 16 + quad * 4;
            #pragma unroll
            for (int jt = 0; jt < 4; ++jt) {
                int bks = (jt * 2 + (r >> 3)) ^ (quad << 1);
                #pragma unroll
                for (int v = 0; v < 4; ++v)
                    p_s[(rowbase + v) * 64 + bks * 8 + (r & 7)] = (_Float16)sc[jt][v];
            }
        }

        f16x8 pa[2];
        #pragma unroll
        for (int cc = 0; cc < 2; ++cc) {
            int rowp = wave * 16 + r;
            int bks = (cc * 4 + quad) ^ (((r >> 2) & 3) << 1);
            pa[cc] = *(const f16x8*)(p_s + rowp * 64 + bks * 8);
        }

        __builtin_amdgcn_s_setprio(1);
        #pragma unroll
        for (int dt = 0; dt < 5; ++dt)
            #pragma unroll
            for (int cc = 0; cc < 2; ++cc) {
                int ck = (cc * 4 + quad) ^ (r & 7);
                f16x8 vbf = *(const f16x8*)(v_s + (dt * 16 + r) * 64 + ck * 8);
                oacc[dt] = __builtin_amdgcn_mfma_f32_16x16x32_f16(pa[cc], vbf, oacc[dt], 0, 0, 0);
            }
        __builtin_amdgcn_s_setprio(0);

        asm volatile("s_waitcnt vmcnt(0)" ::: "memory");
        __builtin_amdgcn_s_barrier();
        cur = nxt;
    }

    float inv_l[4];
    #pragma unroll
    for (int v = 0; v < 4; ++v) {
        float l = l_part[v];
        l += __shfl_xor(l, 1);
        l += __shfl_xor(l, 2);
        l += __shfl_xor(l, 4);
        l += __shfl_xor(l, 8);
        inv_l[v] = 1.0f / l;
    }

    __syncthreads();
    #pragma unroll
    for (int v = 0; v < 4; ++v) {
        int row = wave * 16 + quad * 4 + v;
        #pragma unroll
        for (int dt = 0; dt < 5; ++dt) {
            float o = oacc[dt][v] * inv_l[v];
            ushort hh, ll;
            splitf16(o, hh, ll);
            lds[row * 80 + dt * 16 + r] = hh;
            lds[10240 + row * 80 + dt * 16 + r] = ll;
        }
    }
    __syncthreads();
    {
        size_t gbase = ((size_t)b * NN + q0) * HIDDEN + h * HD;
        #pragma unroll
        for (int i = 0; i < 5; ++i) {
            int u = tid + i * 512;            // 0..2559
            int plane = u / 1280, idx = u % 1280;
            int row = idx / 10, part = idx % 10;
            uint4 w = *(const uint4*)(lds + plane * 10240 + idx * 8);
            ushort* dst = (plane ? ao_lo : ao_hi) + gbase + (size_t)row * HIDDEN + part * 8;
            *(uint4*)dst = w;
        }
    }
}

// ---------------------------------------------------------------------------
extern "C" void kernel_launch(void* const* d_in, const int* in_sizes, int n_in,
                              void* d_out, int out_size, void* d_ws, size_t ws_size,
                              hipStream_t stream)
{
    const float* x      = (const float*)d_in[0];
    const float* cos_t  = (const float*)d_in[1];
    const float* sin_t  = (const float*)d_in[2];
    const float* qkv_w  = (const float*)d_in[3];
    const float* qkv_b  = (const float*)d_in[4];
    const float* proj_w = (const float*)d_in[5];
    const float* proj_b = (const float*)d_in[6];
    float* out = (float*)d_out;

    char* ws = (char*)d_ws;
    // layout (bytes), phase-based reuse:
    //   [0, 62914560)           qkv fp32 (gemm1 out; dead after rope_split)
    //       -> ao_hi @0 (10485760), ao_lo @10485760 (attn out, fp16 hi/lo)
    //   [62914560, 72744960)    wT fp16 (qkv_w^T); after gemm1:
    //       -> vt fp16 @62914560 (10485760, ends 73400320)
    //   [82575360, 103546880)   x split fp16 hi/lo (gemm1 A); after gemm1:
    //       -> qf @83886080 (12582912), kf @96468992 (ends 109051904)
    //   [109051904, 112328704)  pT fp16 (proj_w^T)
    float*  qkv   = (float*)ws;
    ushort* ao_hi = (ushort*)ws;
    ushort* ao_lo = (ushort*)(ws + 10485760);
    ushort* wT    = (ushort*)(ws + 62914560);
    ushort* vt    = (ushort*)(ws + 62914560);
    ushort* a_hi  = (ushort*)(ws + 82575360);
    ushort* a_lo  = (ushort*)(ws + 93061120);
    ushort* q_f   = (ushort*)(ws + 83886080);
    ushort* k_f   = (ushort*)(ws + 96468992);
    ushort* pT    = (ushort*)(ws + 109051904);

    // 1) fused prep: split x -> hi/lo, transpose qkv_w -> wT, proj_w -> pT
    prep_kernel<<<dim3(11520), 256, 0, stream>>>(
        x, a_hi, a_lo, qkv_w, wT, proj_w, pT);

    // 2) qkv = x @ qkv_w + qkv_b   (256x128 v2 4-phase — measured best)
    gemm_f16x2_256x128_kernel<<<dim3((MROWS / 256) * (3 * HIDDEN / 128)), 512, 0, stream>>>(
        a_hi, a_lo, wT, qkv_b, qkv, MROWS, 3 * HIDDEN, HIDDEN, 3 * HIDDEN / 128);

    // 3) RoPE + fp16 relayout (overwrites wT and x-split regions — both dead)
    rope_split_kernel<<<dim3(NN / 64, HEADS, BB), 256, 0, stream>>>(
        qkv, cos_t, sin_t, q_f, k_f, vt);

    // 4) MFMA flash attention v6 (8 waves, LDS-staged)
    attn_mfma_kernel<<<dim3(NN / 128, HEADS, BB), 512, 0, stream>>>(
        q_f, k_f, vt, ao_hi, ao_lo);

    // 5) out = attn_out @ proj_w + proj_b  (128^2 double-buffered, the
    //    round-8 winner: ~27 us)
    gemm_f16x2_kernel<<<dim3(HIDDEN / BN, MROWS / BM), 256, 0, stream>>>(
        ao_hi, ao_lo, pT, proj_b, out, MROWS, HIDDEN, HIDDEN);
}